// Round 11
// baseline (196.984 us; speedup 1.0000x reference)
//
#include <hip/hip_runtime.h>
#include <math.h>

#define N_POINTS 4000000
#define N_PLANES 64
#define THRESH   0.02f
#define NVALS    (N_PLANES*10)              // 640
#define PPT      16                         // points per lane (register-resident)
#define BLKPTS   (PPT*64)                   // 1024 points per item
#define G1       1024                       // reduce grid (4 blocks/CU exactly)
#define ITEMS    4                          // items per block (uniform)
#define NPB      (G1*ITEMS)                 // 4096 items
#define NPAD     (NPB*BLKPTS - N_POINTS)    // 194,304 zero-padded points
#define FULL_PB  (N_POINTS/BLKPTS)          // 3906: items < this are fully valid
#define SEG_R    16                         // rotations per item
#define RTHR     256                        // 4 waves per block

// ---------------------------------------------------------------------------
// Stage 1: systolic-rotation moment reduction, balanced + DS-diluted.
// Lane l holds 16 points (single-buffered) + one resident plane (4 params +
// 10 f32 acc). Inner loop = pure 18-op VALU per (point,plane) pair. Every 16
// point-passes the plane state rotates one lane via 14 ds_bpermute. Acc and
// params persist across the block's 4 items (segment advances per item:
// wave w covers plane-segment (w+it)&3 of item it -> exact 1x coverage).
// Grid 1024 x 4 items: every block identical work, fully co-resident.
// Zero-pads contribute only to cnt (iff |d_p|<THRESH); finalize subtracts.
// ---------------------------------------------------------------------------
__device__ __forceinline__ float bperm(int addr, float v) {
    return __uint_as_float(__builtin_amdgcn_ds_bpermute(addr, __float_as_uint(v)));
}

__global__ __launch_bounds__(RTHR, 4)
void reduce_kernel(const float* __restrict__ pts,
                   const float* __restrict__ nrm,
                   const float* __restrict__ dst,
                   float* __restrict__ partials)
{
    const int lane = threadIdx.x & 63;
    const int wid  = threadIdx.x >> 6;

    __shared__ float part[RTHR/64][NVALS];

    const int rotaddr = ((lane + 1) & 63) << 2;   // pull from lane+1 (shift down)

    // resident plane params: start plane (lane + 16*wid); rotate continuously.
    float cnx, cny, cnz, cnd;
    {
        const int q = (lane + SEG_R * wid) & 63;
        cnx = nrm[q*3+0]; cny = nrm[q*3+1]; cnz = nrm[q*3+2]; cnd = -dst[q];
    }

    float a0=0.f,a1=0.f,a2=0.f,a3=0.f,a4=0.f,a5=0.f,a6=0.f,a7=0.f,a8=0.f,a9=0.f;
    float PX[PPT], PY[PPT], PZ[PPT];

    for (int it = 0; it < ITEMS; ++it) {
        const int pb = blockIdx.x * ITEMS + it;

        // ---- load this item's 1024 points (lane-private 16, coalesced) ----
        const float* P0 = pts + ((size_t)pb * BLKPTS + lane) * 3;
        if (pb < FULL_PB) {                       // fully valid (fast path)
#pragma unroll
            for (int u = 0; u < PPT; ++u) {
                PX[u] = P0[u*192+0]; PY[u] = P0[u*192+1]; PZ[u] = P0[u*192+2];
            }
        } else if (pb == FULL_PB) {               // first 256 points valid: u<4
#pragma unroll
            for (int u = 0; u < PPT; ++u) {
                if (u < 4) { PX[u] = P0[u*192+0]; PY[u] = P0[u*192+1]; PZ[u] = P0[u*192+2]; }
                else       { PX[u] = 0.f; PY[u] = 0.f; PZ[u] = 0.f; }
            }
        } else {                                  // pure pad item
#pragma unroll
            for (int u = 0; u < PPT; ++u) { PX[u] = 0.f; PY[u] = 0.f; PZ[u] = 0.f; }
        }

        // ---- 16 rotations x 16 points ----
#pragma unroll 1
        for (int r = 0; r < SEG_R; ++r) {
#pragma unroll
            for (int u = 0; u < PPT; ++u) {
                const float x = PX[u], y = PY[u], z = PZ[u];
                const float t  = fmaf(x, cnx, fmaf(y, cny, fmaf(z, cnz, cnd)));
                const bool  m  = fabsf(t) < THRESH;
                const float fm = m ? 1.0f : 0.0f;
                const float tx = m ? x : 0.0f;
                const float ty = m ? y : 0.0f;
                const float tz = m ? z : 0.0f;
                a0 += fm;
                a1 += tx; a2 += ty; a3 += tz;
                a4 = fmaf(tx, x, a4); a5 = fmaf(tx, y, a5); a6 = fmaf(tx, z, a6);
                a7 = fmaf(ty, y, a7); a8 = fmaf(ty, z, a8); a9 = fmaf(tz, z, a9);
            }
            // rotate plane state one lane over
            cnx = bperm(rotaddr, cnx); cny = bperm(rotaddr, cny);
            cnz = bperm(rotaddr, cnz); cnd = bperm(rotaddr, cnd);
            a0 = bperm(rotaddr, a0); a1 = bperm(rotaddr, a1);
            a2 = bperm(rotaddr, a2); a3 = bperm(rotaddr, a3);
            a4 = bperm(rotaddr, a4); a5 = bperm(rotaddr, a5);
            a6 = bperm(rotaddr, a6); a7 = bperm(rotaddr, a7);
            a8 = bperm(rotaddr, a8); a9 = bperm(rotaddr, a9);
        }
    }

    // after 64 rotations the acc is back at its start lane:
    // lane l holds the block-total for plane (l + 16*wid) & 63
    {
        const int wp = (lane + SEG_R * wid) & 63;
        float* rr = &part[wid][wp * 10];
        rr[0]=a0; rr[1]=a1; rr[2]=a2; rr[3]=a3; rr[4]=a4;
        rr[5]=a5; rr[6]=a6; rr[7]=a7; rr[8]=a8; rr[9]=a9;
    }
    __syncthreads();
    for (int v = threadIdx.x; v < NVALS; v += RTHR) {
        float sum = 0.f;
#pragma unroll
        for (int ww = 0; ww < RTHR/64; ++ww) sum += part[ww][v];
        partials[(long long)blockIdx.x * NVALS + v] = sum;
    }
}

// ---------------------------------------------------------------------------
// Stage 2 (fused fit): one block per plane. Stream partials, f64-accumulate,
// subtract the deterministic zero-pad cnt contamination, then thread 0 runs
// the 3x3 Jacobi eigensolve and writes the merged param row:
//   {nx, ny, nz, -d, vld*rx, vld*ry, vld*rz, -vld*rd}
// ---------------------------------------------------------------------------
__global__ __launch_bounds__(256)
void finalize_kernel(const float* __restrict__ partials, int nb,
                     const float* __restrict__ nrm,
                     const float* __restrict__ dst,
                     float* __restrict__ params)
{
    const int p    = blockIdx.x;
    const int lane = threadIdx.x & 63;
    const int wid  = threadIdx.x >> 6;

    double s[10];
#pragma unroll
    for (int q = 0; q < 10; ++q) s[q] = 0.0;

    for (int b = threadIdx.x; b < nb; b += 256) {
        const float* row = partials + (long long)b * NVALS + p * 10;
#pragma unroll
        for (int q = 0; q < 10; ++q) s[q] += (double)row[q];
    }

#pragma unroll
    for (int off = 32; off; off >>= 1)
#pragma unroll
        for (int q = 0; q < 10; ++q) s[q] += __shfl_xor(s[q], off);

    __shared__ double wsum[4][10];
    if (lane == 0) {
#pragma unroll
        for (int q = 0; q < 10; ++q) wsum[wid][q] = s[q];
    }
    __syncthreads();
    if (threadIdx.x != 0) return;

    double acc[10];
#pragma unroll
    for (int q = 0; q < 10; ++q)
        acc[q] = wsum[0][q] + wsum[1][q] + wsum[2][q] + wsum[3][q];

    double cnt = acc[0];
    // exact removal of zero-pad contamination: each of the NPAD (0,0,0) pads
    // hit every plane once and contributed [ |-d_p| < THRESH ] to cnt only.
    if (fabsf(dst[p]) < THRESH) cnt -= (double)NPAD;

    const double sx = acc[1], sy = acc[2], sz = acc[3];
    const double den = fmax(cnt, 1.0);
    const double cx = sx / den, cy = sy / den, cz = sz / den;

    double C[3][3];
    C[0][0] = acc[4] - 2.0*cx*sx + cnt*cx*cx;
    C[0][1] = acc[5] - cx*sy - cy*sx + cnt*cx*cy;
    C[0][2] = acc[6] - cx*sz - cz*sx + cnt*cx*cz;
    C[1][1] = acc[7] - 2.0*cy*sy + cnt*cy*cy;
    C[1][2] = acc[8] - cy*sz - cz*sy + cnt*cy*cz;
    C[2][2] = acc[9] - 2.0*cz*sz + cnt*cz*cz;
    C[1][0] = C[0][1]; C[2][0] = C[0][2]; C[2][1] = C[1][2];

    const double valid = (cnt >= 3.0) ? 1.0 : 0.0;
    C[0][0] += (1.0 - valid) * 1.0;
    C[1][1] += (1.0 - valid) * 2.0;
    C[2][2] += (1.0 - valid) * 3.0;

    double V[3][3] = {{1,0,0},{0,1,0},{0,0,1}};
    for (int sweep = 0; sweep < 15; ++sweep) {
#pragma unroll
        for (int k = 0; k < 3; ++k) {
            const int pp = (k == 2) ? 1 : 0;
            const int qq = (k == 0) ? 1 : 2;
            const int rr = 3 - pp - qq;
            const double apq = C[pp][qq];
            if (fabs(apq) < 1e-300) continue;
            const double theta = (C[qq][qq] - C[pp][pp]) / (2.0 * apq);
            const double t = copysign(1.0, theta) / (fabs(theta) + sqrt(theta*theta + 1.0));
            const double c = 1.0 / sqrt(t*t + 1.0);
            const double ss = t * c;
            const double app = C[pp][pp], aqq = C[qq][qq];
            const double arp = C[rr][pp], arq = C[rr][qq];
            C[pp][pp] = app - t * apq;
            C[qq][qq] = aqq + t * apq;
            C[pp][qq] = 0.0; C[qq][pp] = 0.0;
            const double nrp = c*arp - ss*arq;
            const double nrq = ss*arp + c*arq;
            C[rr][pp] = nrp; C[pp][rr] = nrp;
            C[rr][qq] = nrq; C[qq][rr] = nrq;
#pragma unroll
            for (int i = 0; i < 3; ++i) {
                const double vip = V[i][pp], viq = V[i][qq];
                V[i][pp] = c*vip - ss*viq;
                V[i][qq] = ss*vip + c*viq;
            }
        }
    }

    int idx = 0;
    if (C[1][1] < C[idx][idx]) idx = 1;
    if (C[2][2] < C[idx][idx]) idx = 2;
    double rx = V[0][idx], ry = V[1][idx], rz = V[2][idx];
    const double inv = 1.0 / sqrt(rx*rx + ry*ry + rz*rz);
    rx *= inv; ry *= inv; rz *= inv;

    const double nxd = (double)nrm[p*3+0];
    const double nyd = (double)nrm[p*3+1];
    const double nzd = (double)nrm[p*3+2];
    if (rx*nxd + ry*nyd + rz*nzd < 0.0) { rx = -rx; ry = -ry; rz = -rz; }
    const double rd = cx*rx + cy*ry + cz*rz;

    const float vldf = (float)valid;
    params[p*8+0] = nrm[p*3+0];
    params[p*8+1] = nrm[p*3+1];
    params[p*8+2] = nrm[p*3+2];
    params[p*8+3] = -dst[p];
    params[p*8+4] = vldf * (float)rx;
    params[p*8+5] = vldf * (float)ry;
    params[p*8+6] = vldf * (float)rz;
    params[p*8+7] = -(vldf * (float)rd);
}

// ---------------------------------------------------------------------------
// Stage 3: projection, 8 points per thread (single co-resident cohort:
// 500K threads = 7816 waves ~ 30.5/CU). Mask expression bit-identical to
// stage 1. vld folded into rv / rdv.
// ---------------------------------------------------------------------------
#define PPTH 8
#define PQ   (N_POINTS / PPTH)   // 500,000

__global__ __launch_bounds__(256)
void project_kernel(const float* __restrict__ pts,
                    const float* __restrict__ params,
                    float* __restrict__ out)
{
    const int tid = blockIdx.x * 256 + threadIdx.x;
    if (tid >= PQ) return;

    float ox[PPTH], oy[PPTH], oz[PPTH];
    float qx[PPTH], qy[PPTH], qz[PPTH];
#pragma unroll
    for (int k = 0; k < PPTH; ++k) {
        const long long i = (long long)tid + (long long)k * PQ;
        ox[k] = pts[i*3+0]; oy[k] = pts[i*3+1]; oz[k] = pts[i*3+2];
        qx[k] = ox[k]; qy[k] = oy[k]; qz[k] = oz[k];
    }

#pragma unroll 2
    for (int p = 0; p < N_PLANES; ++p) {
        const float nx  = params[p*8+0];
        const float ny  = params[p*8+1];
        const float nz  = params[p*8+2];
        const float md  = params[p*8+3];   // -d
        const float rvx = params[p*8+4];   // vld*rx
        const float rvy = params[p*8+5];
        const float rvz = params[p*8+6];
        const float mrd = params[p*8+7];   // -vld*rd

#pragma unroll
        for (int k = 0; k < PPTH; ++k) {
            const float t0 = fmaf(ox[k], nx, fmaf(oy[k], ny, fmaf(oz[k], nz, md)));
            const float t  = fmaf(qx[k], rvx, fmaf(qy[k], rvy, fmaf(qz[k], rvz, mrd)));
            const float tm = (fabsf(t0) < THRESH) ? t : 0.0f;
            qx[k] = fmaf(-tm, rvx, qx[k]);
            qy[k] = fmaf(-tm, rvy, qy[k]);
            qz[k] = fmaf(-tm, rvz, qz[k]);
        }
    }

#pragma unroll
    for (int k = 0; k < PPTH; ++k) {
        const long long i = (long long)tid + (long long)k * PQ;
        out[i*3+0] = qx[k];
        out[i*3+1] = qy[k];
        out[i*3+2] = qz[k];
    }
}

// ---------------------------------------------------------------------------
extern "C" void kernel_launch(void* const* d_in, const int* in_sizes, int n_in,
                              void* d_out, int out_size, void* d_ws, size_t ws_size,
                              hipStream_t stream)
{
    const float* pts = (const float*)d_in[0];
    const float* nrm = (const float*)d_in[1];
    const float* dst = (const float*)d_in[2];
    float* out = (float*)d_out;

    float* partials = (float*)d_ws;                         // G1 x 640 f32 (2.62 MB)
    size_t poff = ((size_t)G1 * NVALS * sizeof(float) + 255) & ~(size_t)255;
    float* params = (float*)((char*)d_ws + poff);

    hipLaunchKernelGGL(reduce_kernel, dim3(G1), dim3(RTHR), 0, stream,
                       pts, nrm, dst, partials);
    hipLaunchKernelGGL(finalize_kernel, dim3(N_PLANES), dim3(256), 0, stream,
                       partials, G1, nrm, dst, params);
    hipLaunchKernelGGL(project_kernel, dim3((PQ + 255) / 256), dim3(256), 0, stream,
                       pts, params, out);
}

// Round 12
// 181.287 us; speedup vs baseline: 1.0866x; 1.0866x over previous
//
#include <hip/hip_runtime.h>
#include <math.h>

#define N_POINTS 4000000
#define N_PLANES 64
#define THRESH   0.02f
#define NVALS    (N_PLANES*10)              // 640
#define PPT      16                         // points per lane (8 packed pairs)
#define NPAIR    (PPT/2)
#define BLKPTS   (PPT*64)                   // 1024 points per item
#define G1       1024                       // reduce grid (4 blocks/CU exactly)
#define ITEMS    4                          // items per block (uniform)
#define NPB      (G1*ITEMS)                 // 4096 items
#define NPAD     (NPB*BLKPTS - N_POINTS)    // 194,304 zero-padded points
#define FULL_PB  (N_POINTS/BLKPTS)          // 3906: items < this are fully valid
#define SEG_R    16                         // rotations per item
#define RTHR     256                        // 4 waves per block

typedef float v2f __attribute__((ext_vector_type(2)));

// ---- packed fp32 primitives (VOP3P) ----
__device__ __forceinline__ v2f pk_fma(v2f a, v2f b, v2f c) {
    v2f d; asm("v_pk_fma_f32 %0, %1, %2, %3" : "=v"(d) : "v"(a), "v"(b), "v"(c)); return d;
}
__device__ __forceinline__ v2f pk_mul(v2f a, v2f b) {
    v2f d; asm("v_pk_mul_f32 %0, %1, %2" : "=v"(d) : "v"(a), "v"(b)); return d;
}
__device__ __forceinline__ v2f pk_mul_clamp(v2f a, v2f b) {
    v2f d; asm("v_pk_mul_f32 %0, %1, %2 clamp" : "=v"(d) : "v"(a), "v"(b)); return d;
}
__device__ __forceinline__ void pk_adda(v2f& acc, v2f a) {
    asm("v_pk_add_f32 %0, %1, %0" : "+v"(acc) : "v"(a));
}
__device__ __forceinline__ void pk_fmaa(v2f& acc, v2f a, v2f b) {
    asm("v_pk_fma_f32 %0, %1, %2, %0" : "+v"(acc) : "v"(a), "v"(b));
}
__device__ __forceinline__ float bperm(int addr, float v) {
    return __uint_as_float(__builtin_amdgcn_ds_bpermute(addr, __float_as_uint(v)));
}

// ---------------------------------------------------------------------------
// Stage 1: systolic-rotation moment reduction, packed fp32.
// Lane l holds 8 point-pairs (v2f) + one resident plane (splatted params +
// 10 packed f32 acc). Inner body = 18 pk inst per pair (9/point): t via 3
// pk_fma; mask fm = clamp((t^2-TH^2) * -1e20) in {0,1}; 3 pk_mul; 10 packed
// accumulates. Rotation: merge acc halves -> 10 scalar bperms -> re-expand
// {s,0}; params rotate via 4 bperms on splat-lo + copy (DS = 14/rot, as r11).
// Coverage identical to r11. Zero-pads contribute only to cnt iff
// fmaf(d,d,-TH^2) < 0; finalize subtracts with the bit-identical predicate.
// ---------------------------------------------------------------------------
__global__ __launch_bounds__(RTHR, 4)
void reduce_kernel(const float* __restrict__ pts,
                   const float* __restrict__ nrm,
                   const float* __restrict__ dst,
                   float* __restrict__ partials)
{
    const int lane = threadIdx.x & 63;
    const int wid  = threadIdx.x >> 6;

    __shared__ float part[RTHR/64][NVALS];

    const int rotaddr = ((lane + 1) & 63) << 2;   // pull from lane+1

    const v2f TH2N2 = { -(THRESH*THRESH), -(THRESH*THRESH) };
    const v2f NBIG2 = { -1e20f, -1e20f };

    // resident plane (lane == start plane (lane + 16*wid)), splatted
    v2f nx2, ny2, nz2, nd2;
    {
        const int q = (lane + SEG_R * wid) & 63;
        const float a = nrm[q*3+0], b = nrm[q*3+1], c = nrm[q*3+2], d = -dst[q];
        nx2 = (v2f){a,a}; ny2 = (v2f){b,b}; nz2 = (v2f){c,c}; nd2 = (v2f){d,d};
    }

    v2f a2[10];
#pragma unroll
    for (int i = 0; i < 10; ++i) a2[i] = (v2f){0.f, 0.f};

    v2f PX2[NPAIR], PY2[NPAIR], PZ2[NPAIR];

    for (int it = 0; it < ITEMS; ++it) {
        const int pb = blockIdx.x * ITEMS + it;
        const float* P0 = pts + ((size_t)pb * BLKPTS + lane) * 3;

        if (pb < FULL_PB) {                       // fully valid (fast path)
#pragma unroll
            for (int v = 0; v < NPAIR; ++v) {
                PX2[v] = (v2f){ P0[(2*v)*192+0], P0[(2*v+1)*192+0] };
                PY2[v] = (v2f){ P0[(2*v)*192+1], P0[(2*v+1)*192+1] };
                PZ2[v] = (v2f){ P0[(2*v)*192+2], P0[(2*v+1)*192+2] };
            }
        } else if (pb == FULL_PB) {               // points valid only for u<4
#pragma unroll
            for (int v = 0; v < NPAIR; ++v) {
                if (v < 2) {
                    PX2[v] = (v2f){ P0[(2*v)*192+0], P0[(2*v+1)*192+0] };
                    PY2[v] = (v2f){ P0[(2*v)*192+1], P0[(2*v+1)*192+1] };
                    PZ2[v] = (v2f){ P0[(2*v)*192+2], P0[(2*v+1)*192+2] };
                } else {
                    PX2[v] = (v2f){0.f,0.f}; PY2[v] = (v2f){0.f,0.f}; PZ2[v] = (v2f){0.f,0.f};
                }
            }
        } else {                                  // pure pad item
#pragma unroll
            for (int v = 0; v < NPAIR; ++v) {
                PX2[v] = (v2f){0.f,0.f}; PY2[v] = (v2f){0.f,0.f}; PZ2[v] = (v2f){0.f,0.f};
            }
        }

#pragma unroll 1
        for (int r = 0; r < SEG_R; ++r) {
#pragma unroll
            for (int v = 0; v < NPAIR; ++v) {
                const v2f t2  = pk_fma(PX2[v], nx2, pk_fma(PY2[v], ny2, pk_fma(PZ2[v], nz2, nd2)));
                const v2f d2  = pk_fma(t2, t2, TH2N2);        // t^2 - TH^2
                const v2f fm2 = pk_mul_clamp(d2, NBIG2);      // 1 iff t^2 < TH^2, else 0
                const v2f tx2 = pk_mul(PX2[v], fm2);
                const v2f ty2 = pk_mul(PY2[v], fm2);
                const v2f tz2 = pk_mul(PZ2[v], fm2);
                pk_adda(a2[0], fm2);
                pk_adda(a2[1], tx2); pk_adda(a2[2], ty2); pk_adda(a2[3], tz2);
                pk_fmaa(a2[4], tx2, PX2[v]); pk_fmaa(a2[5], tx2, PY2[v]); pk_fmaa(a2[6], tx2, PZ2[v]);
                pk_fmaa(a2[7], ty2, PY2[v]); pk_fmaa(a2[8], ty2, PZ2[v]); pk_fmaa(a2[9], tz2, PZ2[v]);
            }
            // rotate: merge packed acc -> 10 scalar bperms -> re-expand {s, 0}
            float s[10];
#pragma unroll
            for (int i = 0; i < 10; ++i) s[i] = a2[i].x + a2[i].y;
#pragma unroll
            for (int i = 0; i < 10; ++i) s[i] = bperm(rotaddr, s[i]);
#pragma unroll
            for (int i = 0; i < 10; ++i) a2[i] = (v2f){ s[i], 0.f };
            // rotate plane splats (lo half via bperm, copy to hi)
            nx2.x = bperm(rotaddr, nx2.x); nx2.y = nx2.x;
            ny2.x = bperm(rotaddr, ny2.x); ny2.y = ny2.x;
            nz2.x = bperm(rotaddr, nz2.x); nz2.y = nz2.x;
            nd2.x = bperm(rotaddr, nd2.x); nd2.y = nd2.x;
        }
    }

    // after 64 rotations acc is back at its start lane:
    // lane l holds the block-total for plane (l + 16*wid) & 63
    {
        const int wp = (lane + SEG_R * wid) & 63;
        float* rr = &part[wid][wp * 10];
#pragma unroll
        for (int i = 0; i < 10; ++i) rr[i] = a2[i].x + a2[i].y;
    }
    __syncthreads();
    for (int v = threadIdx.x; v < NVALS; v += RTHR) {
        float sum = 0.f;
#pragma unroll
        for (int ww = 0; ww < RTHR/64; ++ww) sum += part[ww][v];
        partials[(long long)blockIdx.x * NVALS + v] = sum;
    }
}

// ---------------------------------------------------------------------------
// Stage 2 (fused fit): one block per plane. Stream partials, f64-accumulate,
// subtract the zero-pad cnt contamination (bit-identical predicate to the
// kernel's packed mask), then thread 0 runs the 3x3 Jacobi eigensolve and
// writes the merged param row {nx,ny,nz,-d, vld*rx,vld*ry,vld*rz, -vld*rd}.
// ---------------------------------------------------------------------------
__global__ __launch_bounds__(256)
void finalize_kernel(const float* __restrict__ partials, int nb,
                     const float* __restrict__ nrm,
                     const float* __restrict__ dst,
                     float* __restrict__ params)
{
    const int p    = blockIdx.x;
    const int lane = threadIdx.x & 63;
    const int wid  = threadIdx.x >> 6;

    double s[10];
#pragma unroll
    for (int q = 0; q < 10; ++q) s[q] = 0.0;

    for (int b = threadIdx.x; b < nb; b += 256) {
        const float* row = partials + (long long)b * NVALS + p * 10;
#pragma unroll
        for (int q = 0; q < 10; ++q) s[q] += (double)row[q];
    }

#pragma unroll
    for (int off = 32; off; off >>= 1)
#pragma unroll
        for (int q = 0; q < 10; ++q) s[q] += __shfl_xor(s[q], off);

    __shared__ double wsum[4][10];
    if (lane == 0) {
#pragma unroll
        for (int q = 0; q < 10; ++q) wsum[wid][q] = s[q];
    }
    __syncthreads();
    if (threadIdx.x != 0) return;

    double acc[10];
#pragma unroll
    for (int q = 0; q < 10; ++q)
        acc[q] = wsum[0][q] + wsum[1][q] + wsum[2][q] + wsum[3][q];

    double cnt = acc[0];
    // pad points (0,0,0): t = -d; mask = (fmaf(t,t,-TH^2) clamped) > 0
    if (fmaf(dst[p], dst[p], -(THRESH*THRESH)) < 0.0f) cnt -= (double)NPAD;

    const double sx = acc[1], sy = acc[2], sz = acc[3];
    const double den = fmax(cnt, 1.0);
    const double cx = sx / den, cy = sy / den, cz = sz / den;

    double C[3][3];
    C[0][0] = acc[4] - 2.0*cx*sx + cnt*cx*cx;
    C[0][1] = acc[5] - cx*sy - cy*sx + cnt*cx*cy;
    C[0][2] = acc[6] - cx*sz - cz*sx + cnt*cx*cz;
    C[1][1] = acc[7] - 2.0*cy*sy + cnt*cy*cy;
    C[1][2] = acc[8] - cy*sz - cz*sy + cnt*cy*cz;
    C[2][2] = acc[9] - 2.0*cz*sz + cnt*cz*cz;
    C[1][0] = C[0][1]; C[2][0] = C[0][2]; C[2][1] = C[1][2];

    const double valid = (cnt >= 3.0) ? 1.0 : 0.0;
    C[0][0] += (1.0 - valid) * 1.0;
    C[1][1] += (1.0 - valid) * 2.0;
    C[2][2] += (1.0 - valid) * 3.0;

    double V[3][3] = {{1,0,0},{0,1,0},{0,0,1}};
    for (int sweep = 0; sweep < 15; ++sweep) {
#pragma unroll
        for (int k = 0; k < 3; ++k) {
            const int pp = (k == 2) ? 1 : 0;
            const int qq = (k == 0) ? 1 : 2;
            const int rr = 3 - pp - qq;
            const double apq = C[pp][qq];
            if (fabs(apq) < 1e-300) continue;
            const double theta = (C[qq][qq] - C[pp][pp]) / (2.0 * apq);
            const double t = copysign(1.0, theta) / (fabs(theta) + sqrt(theta*theta + 1.0));
            const double c = 1.0 / sqrt(t*t + 1.0);
            const double ss = t * c;
            const double app = C[pp][pp], aqq = C[qq][qq];
            const double arp = C[rr][pp], arq = C[rr][qq];
            C[pp][pp] = app - t * apq;
            C[qq][qq] = aqq + t * apq;
            C[pp][qq] = 0.0; C[qq][pp] = 0.0;
            const double nrp = c*arp - ss*arq;
            const double nrq = ss*arp + c*arq;
            C[rr][pp] = nrp; C[pp][rr] = nrp;
            C[rr][qq] = nrq; C[qq][rr] = nrq;
#pragma unroll
            for (int i = 0; i < 3; ++i) {
                const double vip = V[i][pp], viq = V[i][qq];
                V[i][pp] = c*vip - ss*viq;
                V[i][qq] = ss*vip + c*viq;
            }
        }
    }

    int idx = 0;
    if (C[1][1] < C[idx][idx]) idx = 1;
    if (C[2][2] < C[idx][idx]) idx = 2;
    double rx = V[0][idx], ry = V[1][idx], rz = V[2][idx];
    const double inv = 1.0 / sqrt(rx*rx + ry*ry + rz*rz);
    rx *= inv; ry *= inv; rz *= inv;

    const double nxd = (double)nrm[p*3+0];
    const double nyd = (double)nrm[p*3+1];
    const double nzd = (double)nrm[p*3+2];
    if (rx*nxd + ry*nyd + rz*nzd < 0.0) { rx = -rx; ry = -ry; rz = -rz; }
    const double rd = cx*rx + cy*ry + cz*rz;

    const float vldf = (float)valid;
    params[p*8+0] = nrm[p*3+0];
    params[p*8+1] = nrm[p*3+1];
    params[p*8+2] = nrm[p*3+2];
    params[p*8+3] = -dst[p];
    params[p*8+4] = vldf * (float)rx;
    params[p*8+5] = vldf * (float)ry;
    params[p*8+6] = vldf * (float)rz;
    params[p*8+7] = -(vldf * (float)rd);
}

// ---------------------------------------------------------------------------
// Stage 3: packed projection, 8 points per thread as 4 pairs (13 pk-inst per
// pair per plane). Same t-chains as before; mask via the packed clamp trick.
// ---------------------------------------------------------------------------
#define PPTH 8
#define PQ   (N_POINTS / PPTH)   // 500,000

__global__ __launch_bounds__(256)
void project_kernel(const float* __restrict__ pts,
                    const float* __restrict__ params,
                    float* __restrict__ out)
{
    const int tid = blockIdx.x * 256 + threadIdx.x;
    if (tid >= PQ) return;

    const v2f TH2N2 = { -(THRESH*THRESH), -(THRESH*THRESH) };
    const v2f NBIG2 = { -1e20f, -1e20f };
    const v2f NEG12 = { -1.f, -1.f };

    v2f ox2[4], oy2[4], oz2[4], qx2[4], qy2[4], qz2[4];
#pragma unroll
    for (int k = 0; k < 4; ++k) {
        const long long i0 = (long long)tid + (long long)(2*k)   * PQ;
        const long long i1 = (long long)tid + (long long)(2*k+1) * PQ;
        ox2[k] = (v2f){ pts[i0*3+0], pts[i1*3+0] };
        oy2[k] = (v2f){ pts[i0*3+1], pts[i1*3+1] };
        oz2[k] = (v2f){ pts[i0*3+2], pts[i1*3+2] };
        qx2[k] = ox2[k]; qy2[k] = oy2[k]; qz2[k] = oz2[k];
    }

#pragma unroll 2
    for (int p = 0; p < N_PLANES; ++p) {
        const float nx  = params[p*8+0];
        const float ny  = params[p*8+1];
        const float nz  = params[p*8+2];
        const float md  = params[p*8+3];   // -d
        const float rvx = params[p*8+4];   // vld*rx
        const float rvy = params[p*8+5];
        const float rvz = params[p*8+6];
        const float mrd = params[p*8+7];   // -vld*rd
        const v2f nx2  = (v2f){nx,nx},   ny2  = (v2f){ny,ny},   nz2 = (v2f){nz,nz};
        const v2f md2  = (v2f){md,md},   mrd2 = (v2f){mrd,mrd};
        const v2f rvx2 = (v2f){rvx,rvx}, rvy2 = (v2f){rvy,rvy}, rvz2 = (v2f){rvz,rvz};

#pragma unroll
        for (int k = 0; k < 4; ++k) {
            const v2f t0  = pk_fma(ox2[k], nx2, pk_fma(oy2[k], ny2, pk_fma(oz2[k], nz2, md2)));
            const v2f d2  = pk_fma(t0, t0, TH2N2);
            const v2f fm2 = pk_mul_clamp(d2, NBIG2);
            const v2f tt  = pk_fma(qx2[k], rvx2, pk_fma(qy2[k], rvy2, pk_fma(qz2[k], rvz2, mrd2)));
            const v2f ftn = pk_mul(pk_mul(tt, fm2), NEG12);   // -fm*t
            qx2[k] = pk_fma(ftn, rvx2, qx2[k]);
            qy2[k] = pk_fma(ftn, rvy2, qy2[k]);
            qz2[k] = pk_fma(ftn, rvz2, qz2[k]);
        }
    }

#pragma unroll
    for (int k = 0; k < 4; ++k) {
        const long long i0 = (long long)tid + (long long)(2*k)   * PQ;
        const long long i1 = (long long)tid + (long long)(2*k+1) * PQ;
        out[i0*3+0] = qx2[k].x; out[i0*3+1] = qy2[k].x; out[i0*3+2] = qz2[k].x;
        out[i1*3+0] = qx2[k].y; out[i1*3+1] = qy2[k].y; out[i1*3+2] = qz2[k].y;
    }
}

// ---------------------------------------------------------------------------
extern "C" void kernel_launch(void* const* d_in, const int* in_sizes, int n_in,
                              void* d_out, int out_size, void* d_ws, size_t ws_size,
                              hipStream_t stream)
{
    const float* pts = (const float*)d_in[0];
    const float* nrm = (const float*)d_in[1];
    const float* dst = (const float*)d_in[2];
    float* out = (float*)d_out;

    float* partials = (float*)d_ws;                         // G1 x 640 f32 (2.62 MB)
    size_t poff = ((size_t)G1 * NVALS * sizeof(float) + 255) & ~(size_t)255;
    float* params = (float*)((char*)d_ws + poff);

    hipLaunchKernelGGL(reduce_kernel, dim3(G1), dim3(RTHR), 0, stream,
                       pts, nrm, dst, partials);
    hipLaunchKernelGGL(finalize_kernel, dim3(N_PLANES), dim3(256), 0, stream,
                       partials, G1, nrm, dst, params);
    hipLaunchKernelGGL(project_kernel, dim3((PQ + 255) / 256), dim3(256), 0, stream,
                       pts, params, out);
}